// Round 6
// baseline (216.378 us; speedup 1.0000x reference)
//
#include <hip/hip_runtime.h>

#define B_ 4
#define S_ 2048
#define E_ 1024
#define H_ 16
#define D_ 64
#define BH_ (B_*H_)
#define SD_ (S_*D_)

// log2(e)/8 : folds both 1/sqrt(D) and the exp->exp2 conversion into Q
#define QSCALE 0.18033688011112042f

typedef __attribute__((ext_vector_type(4))) float f32x4;
typedef __attribute__((ext_vector_type(16))) float f32x16;
typedef __attribute__((ext_vector_type(8))) short bf16x8;
typedef __attribute__((ext_vector_type(2))) unsigned int uint2v;

#define MFMA(a,b,c)   __builtin_amdgcn_mfma_f32_16x16x32_bf16((a),(b),(c),0,0,0)
#define MFMA32(a,b,c) __builtin_amdgcn_mfma_f32_32x32x16_bf16((a),(b),(c),0,0,0)

__device__ __forceinline__ unsigned short f2bf(float f) {
    unsigned int u = __float_as_uint(f);
    unsigned int r = (u + 0x7fffu + ((u >> 16) & 1u)) >> 16;   // RNE
    return (unsigned short)r;
}
__device__ __forceinline__ unsigned int cvtpk(float a, float b) {
    unsigned int r;
    asm("v_cvt_pk_bf16_f32 %0, %1, %2" : "=v"(r) : "v"(a), "v"(b));
    return r;
}
__device__ __forceinline__ float exp2fast(float x) {
    float r;
    asm("v_exp_f32 %0, %1" : "=v"(r) : "v"(x));
    return r;
}
__device__ __forceinline__ float max3f(float a, float b, float c) {
    float r;
    asm("v_max3_f32 %0, %1, %2, %3" : "=v"(r) : "v"(a), "v"(b), "v"(c));
    return r;
}
__device__ __forceinline__ void gload16(const void* g, void* l) {
    __builtin_amdgcn_global_load_lds(
        (const __attribute__((address_space(1))) unsigned int*)g,
        (__attribute__((address_space(3))) unsigned int*)l, 16, 0, 0);
}

// ---------------------------------------------------------------------------
// prep: W[h][d][e] fp32 -> Wt[mat][h][e][d] bf16 (Q pre-scaled), bias fp32
// ---------------------------------------------------------------------------
__global__ __launch_bounds__(256) void prep_kernel(
    const float* __restrict__ Wq, const float* __restrict__ bq,
    const float* __restrict__ Wk, const float* __restrict__ bk,
    const float* __restrict__ Wv, const float* __restrict__ bv,
    unsigned short* __restrict__ wt, float* __restrict__ bias)
{
    const int blk = blockIdx.x;            // 192 = 3 mats * 16 heads * 4 dchunks
    const int mat = blk >> 6, rest = blk & 63;
    const int h = rest >> 2, dc = rest & 3;
    const float* W    = (mat == 0) ? Wq : (mat == 1) ? Wk : Wv;
    const float* bsrc = (mat == 0) ? bq : (mat == 1) ? bk : bv;
    const float scale = (mat == 0) ? QSCALE : 1.0f;
    const int tid = threadIdx.x;
#pragma unroll
    for (int i = 0; i < 4; ++i) {
        int idx = tid + i * 256;           // 0..1023
        int d = dc * 16 + (idx >> 6), e = idx & 63;
        wt[((mat * H_ + h) << 12) + e * 64 + d] = f2bf(W[h * 4096 + d * 64 + e] * scale);
    }
    if (dc == 0 && tid < 64) bias[(mat * H_ + h) * 64 + tid] = bsrc[h * 64 + tid] * scale;
}

// ---------------------------------------------------------------------------
// proj: Q -> [bh][s][d] bf16 (row layout);
//       K,V -> TILED+SWIZZLED [bh][t][4096] bf16 (LDS image), built in LDS
//       then written out with fully-coalesced 16B stores.
// ---------------------------------------------------------------------------
__global__ __launch_bounds__(256) void proj_kernel(
    const float* __restrict__ x,
    const unsigned short* __restrict__ wt,
    const float* __restrict__ bias,
    unsigned short* __restrict__ Qg,
    unsigned short* __restrict__ Kg,
    unsigned short* __restrict__ Vtg)
{
    __shared__ unsigned short x_lds[64 * 64];      // 8 KiB; later reused as K image
    __shared__ unsigned short w_lds[3][64 * 64];   // 24 KiB; [0] later reused as V image

    const int blk = blockIdx.x;                    // 2048
    const int bh  = blk >> 5;
    const int t_  = blk & 31;                      // s-tile index
    const int s0  = t_ << 6;
    const int batch = bh >> 4, h = bh & 15;
    const int tid = threadIdx.x, lane = tid & 63, w = tid >> 6;
    const int lo = lane & 15, hi = lane >> 4;

    // stage X tile (64 s-rows x 64 d) fp32->bf16, swizzled
#pragma unroll
    for (int rnd = 0; rnd < 4; ++rnd) {
        int c = tid + rnd * 256;                   // 0..1023 chunks of 4 floats
        int row = c >> 4, sl4 = c & 15;
        float4 xv = *(const float4*)(x + (size_t)(batch * S_ + s0 + row) * E_ + h * 64 + sl4 * 4);
        int off = row * 64 + (((sl4 >> 1) ^ (row & 7)) << 3) + ((sl4 & 1) << 2);
        uint2 pk;
        pk.x = cvtpk(xv.x, xv.y);
        pk.y = cvtpk(xv.z, xv.w);
        *(uint2*)(x_lds + off) = pk;
    }
    // stage Wt (3 x 64e x 64d bf16), swizzled
#pragma unroll
    for (int rnd = 0; rnd < 6; ++rnd) {
        int c = tid + rnd * 256;                   // 0..1535 chunks of 16B
        int mat = c >> 9, cc = c & 511;
        int row = cc >> 3, slot = cc & 7;
        *(uint4*)(w_lds[mat] + row * 64 + ((slot ^ (row & 7)) << 3)) =
            *(const uint4*)(wt + ((mat * H_ + h) << 12) + row * 64 + slot * 8);
    }
    __syncthreads();

    // this wave's s-chunk x fragments (shared by Q/K B-operand and V A-operand)
    const int xrow = w * 16 + lo;
    bf16x8 xf0 = *(const bf16x8*)(x_lds + xrow * 64 + ((hi ^ (xrow & 7)) << 3));
    bf16x8 xf1 = *(const bf16x8*)(x_lds + xrow * 64 + (((4 + hi) ^ (xrow & 7)) << 3));
    __syncthreads();   // all waves hold xf in regs; x_lds free for reuse as K image

    // Q, K: C[e][s] = Wt . X^T  -> thread holds e = et*16+hi*4+(0..3), s = w*16+lo
#pragma unroll
    for (int mat = 0; mat < 2; ++mat) {
        const unsigned short* wl = w_lds[mat];
#pragma unroll
        for (int et = 0; et < 4; ++et) {
            int erow = et * 16 + lo;
            bf16x8 wa0 = *(const bf16x8*)(wl + erow * 64 + ((hi ^ (erow & 7)) << 3));
            bf16x8 wa1 = *(const bf16x8*)(wl + erow * 64 + (((4 + hi) ^ (erow & 7)) << 3));
            f32x4 acc = {0.f, 0.f, 0.f, 0.f};
            acc = MFMA(wa0, xf0, acc);
            acc = MFMA(wa1, xf1, acc);
            f32x4 bv = *(const f32x4*)(bias + (mat * H_ + h) * 64 + et * 16 + hi * 4);
            acc += bv;
            uint2 pk;
            pk.x = cvtpk(acc[0], acc[1]);
            pk.y = cvtpk(acc[2], acc[3]);
            if (mat == 0) {
                // Q: plain row layout [s][e]
                *(uint2*)(Qg + bh * SD_ + (s0 + w * 16 + lo) * 64 + et * 16 + hi * 4) = pk;
            } else {
                // K image -> LDS (x_lds)
                int row = w * 16 + lo;
                int sl  = et * 2 + (hi >> 1);
                int b8  = (row * 8 + (sl ^ (row & 7))) * 2 + (hi & 1);
                *(uint2*)(x_lds + b8 * 4) = pk;
            }
        }
    }
    __syncthreads();   // K image complete; w_lds[0] no longer read

    // V: C[s][e] = X . Wv  -> thread holds s = w*16+hi*4+(0..3), e = nt*16+lo
#pragma unroll
    for (int nt = 0; nt < 4; ++nt) {
        int erow = nt * 16 + lo;
        bf16x8 wb0 = *(const bf16x8*)(w_lds[2] + erow * 64 + ((hi ^ (erow & 7)) << 3));
        bf16x8 wb1 = *(const bf16x8*)(w_lds[2] + erow * 64 + (((4 + hi) ^ (erow & 7)) << 3));
        f32x4 acc = {0.f, 0.f, 0.f, 0.f};
        acc = MFMA(xf0, wb0, acc);
        acc = MFMA(xf1, wb1, acc);
        float bvv = bias[(2 * H_ + h) * 64 + nt * 16 + lo];
        acc += bvv;
        uint2 pk;
        pk.x = cvtpk(acc[0], acc[1]);
        pk.y = cvtpk(acc[2], acc[3]);
        int row = nt * 16 + lo;
        int sl  = w * 2 + (hi >> 1);
        int b8  = (row * 8 + (sl ^ (row & 7))) * 2 + (hi & 1);
        *(uint2*)(w_lds[0] + b8 * 4) = pk;       // V image -> LDS
    }
    __syncthreads();

    // coalesced copy-out of both images (16B per lane, fully contiguous)
    unsigned short* Kdst = Kg  + bh * SD_ + t_ * 4096;
    unsigned short* Vdst = Vtg + bh * SD_ + t_ * 4096;
#pragma unroll
    for (int r = 0; r < 2; ++r) {
        int c = tid + r * 256;                   // 0..511 chunks of 16B
        *(uint4*)(Kdst + c * 8) = *(const uint4*)(x_lds + c * 8);
        *(uint4*)(Vdst + c * 8) = *(const uint4*)(w_lds[0] + c * 8);
    }
}

// ---------------------------------------------------------------------------
// attn: flash attention, swapped QK^T with 32x32x16 MFMA, KVBLK=64,
// 4 waves x 32 q (QBLK=128); global_load_lds double-buffer; m folded into
// MFMA C-init (persistent); l via ones-MFMA accumulated across tiles;
// P->B-frag via 2x permlane32_swap per k-subtile (m214 recipe, zero selects)
// ---------------------------------------------------------------------------
__global__ __launch_bounds__(256, 4) void attn_kernel(
    const unsigned short* __restrict__ Qg,
    const unsigned short* __restrict__ Kg,
    const unsigned short* __restrict__ Vtg,
    float* __restrict__ outp)
{
    __shared__ unsigned short k_lds[2][64 * 64];   // K image  (8 KiB each)
    __shared__ unsigned short v_lds[2][64 * 64];   // Vt image

    const int blk = blockIdx.x;                 // 1024, XCD-bijective swizzle
    const int bh  = (blk & 7) + ((blk >> 7) << 3);
    const int qt  = (blk >> 3) & 15;
    const int batch = bh >> 4, hd = bh & 15;
    const int tid = threadIdx.x, lane = tid & 63, w = tid >> 6;  // w = 0..3
    const int l31 = lane & 31, l5 = lane >> 5;
    const int q0 = qt * 128 + w * 32;

    const unsigned short* Qb = Qg + bh * SD_;
    const char* Kt = (const char*)(Kg  + bh * SD_);   // tiled: +t*8192 bytes
    const char* Vt = (const char*)(Vtg + bh * SD_);

    // Q B-frags (scale pre-folded): lane holds Q[q0+l31][ds*16 + l5*8 .. +8]
    bf16x8 qf[4];
#pragma unroll
    for (int ds = 0; ds < 4; ++ds)
        qf[ds] = *(const bf16x8*)(Qb + (q0 + l31) * 64 + ds * 16 + l5 * 8);

    bf16x8 ones8;
#pragma unroll
    for (int j = 0; j < 8; ++j) ones8[j] = (short)0x3F80;

    const int goff = w * 1024 + lane * 16;   // byte offset of this lane's chunk
    const int lds0 = w * 512;                // element offset of wave's LDS chunk

    f32x16 o2[2], lzacc, mi;
#pragma unroll
    for (int i = 0; i < 16; ++i) {
        o2[0][i] = 0.f; o2[1][i] = 0.f; lzacc[i] = 0.f; mi[i] = 0.f;
    }
    float m_run = 0.0f;

    const int swz = (l31 & 7);

    // prologue: stage tile 0 into buf0
    gload16(Kt + goff,        &k_lds[0][lds0]);
    gload16(Kt + goff + 4096, &k_lds[0][lds0 + 2048]);
    gload16(Vt + goff,        &v_lds[0][lds0]);
    gload16(Vt + goff + 4096, &v_lds[0][lds0 + 2048]);
    __syncthreads();

#pragma unroll 1
    for (int t = 0; t < 32; ++t) {
        const unsigned short* kl = k_lds[t & 1];
        const unsigned short* vl = v_lds[t & 1];
        if (t + 1 < 32) {
            const int nb = (t + 1) & 1;
            const int tb = (t + 1) * 8192;
            gload16(Kt + tb + goff,        &k_lds[nb][lds0]);
            gload16(Kt + tb + goff + 4096, &k_lds[nb][lds0 + 2048]);
            gload16(Vt + tb + goff,        &v_lds[nb][lds0]);
            gload16(Vt + tb + goff + 4096, &v_lds[nb][lds0 + 2048]);
        }

        // S^T[k][q] - m = K . Q^T + mi   (2 k-subtiles of 32)
        f32x16 st0 = mi, st1 = mi;
        __builtin_amdgcn_s_setprio(1);
#pragma unroll
        for (int ds = 0; ds < 4; ++ds) {
            const int so = (((ds << 1) + l5) ^ swz) << 3;
            bf16x8 ka0 = *(const bf16x8*)(kl + l31 * 64 + so);
            bf16x8 ka1 = *(const bf16x8*)(kl + 2048 + l31 * 64 + so);
            st0 = MFMA32(ka0, qf[ds], st0);
            st1 = MFMA32(ka1, qf[ds], st1);
        }
        __builtin_amdgcn_s_setprio(0);

        // row max of 32 shifted scores (max3 tree) + cross-half reduce
        float c0 = max3f(st0[0], st0[1], st0[2]);
        float c1 = max3f(st0[3], st0[4], st0[5]);
        float c2 = max3f(st0[6], st0[7], st0[8]);
        float c3 = max3f(st0[9], st0[10], st0[11]);
        float c4 = max3f(st0[12], st0[13], st0[14]);
        float c5 = max3f(st0[15], st1[0], st1[1]);
        float c6 = max3f(st1[2], st1[3], st1[4]);
        float c7 = max3f(st1[5], st1[6], st1[7]);
        float c8 = max3f(st1[8], st1[9], st1[10]);
        float c9 = max3f(st1[11], st1[12], st1[13]);
        float ca = fmaxf(st1[14], st1[15]);
        float d0 = max3f(c0, c1, c2);
        float d1 = max3f(c3, c4, c5);
        float d2 = max3f(c6, c7, c8);
        float d3 = max3f(c9, ca, d0);
        float mx = max3f(d1, d2, d3);
        mx = fmaxf(mx, __shfl_xor(mx, 32));

        // defer-max (T13): rescale only when max grew by > 8 over m_run
        if (!__all(mx <= 8.0f)) {
            float delta = fmaxf(mx, 0.0f);
            float alpha = exp2fast(-delta);
#pragma unroll
            for (int i = 0; i < 16; ++i) {
                o2[0][i] *= alpha; o2[1][i] *= alpha; lzacc[i] *= alpha;
                st0[i] -= delta;   st1[i] -= delta;   mi[i]   -= delta;
            }
            m_run += delta;
        }

        // P = exp2(st) -> bf16 pairs -> B-frags via permlane32_swap
        union F { bf16x8 v; unsigned int u[4]; };
        F pb[2][2];
#pragma unroll
        for (int kt = 0; kt < 2; ++kt) {
            const f32x16& s = kt ? st1 : st0;
            unsigned int u0 = cvtpk(exp2fast(s[0]),  exp2fast(s[1]));
            unsigned int u1 = cvtpk(exp2fast(s[2]),  exp2fast(s[3]));
            unsigned int u2 = cvtpk(exp2fast(s[4]),  exp2fast(s[5]));
            unsigned int u3 = cvtpk(exp2fast(s[6]),  exp2fast(s[7]));
            unsigned int u4 = cvtpk(exp2fast(s[8]),  exp2fast(s[9]));
            unsigned int u5 = cvtpk(exp2fast(s[10]), exp2fast(s[11]));
            unsigned int u6 = cvtpk(exp2fast(s[12]), exp2fast(s[13]));
            unsigned int u7 = cvtpk(exp2fast(s[14]), exp2fast(s[15]));
            uint2v sA = __builtin_amdgcn_permlane32_swap(u0, u2, false, false);
            uint2v sB = __builtin_amdgcn_permlane32_swap(u1, u3, false, false);
            pb[kt][0].u[0] = sA.x; pb[kt][0].u[1] = sB.x;
            pb[kt][0].u[2] = sA.y; pb[kt][0].u[3] = sB.y;
            uint2v sC = __builtin_amdgcn_permlane32_swap(u4, u6, false, false);
            uint2v sD = __builtin_amdgcn_permlane32_swap(u5, u7, false, false);
            pb[kt][1].u[0] = sC.x; pb[kt][1].u[1] = sD.x;
            pb[kt][1].u[2] = sC.y; pb[kt][1].u[3] = sD.y;
        }

        // l row-sum via ones-MFMA (accumulated across tiles) + O += V^T . P^T
        __builtin_amdgcn_s_setprio(1);
        lzacc = MFMA32(ones8, pb[0][0].v, lzacc);
        lzacc = MFMA32(ones8, pb[0][1].v, lzacc);
        lzacc = MFMA32(ones8, pb[1][0].v, lzacc);
        lzacc = MFMA32(ones8, pb[1][1].v, lzacc);
#pragma unroll
        for (int dt = 0; dt < 2; ++dt) {
#pragma unroll
            for (int ksb = 0; ksb < 4; ++ksb) {
                bf16x8 va = *(const bf16x8*)(vl + dt * 2048 + l31 * 64 +
                                             ((((ksb << 1) + l5) ^ swz) << 3));
                o2[dt] = MFMA32(va, pb[ksb >> 1][ksb & 1].v, o2[dt]);
            }
        }
        __builtin_amdgcn_s_setprio(0);

        __syncthreads();
    }

    const float inv = 1.0f / lzacc[0];
    float* ob = outp + (size_t)(batch * S_ + q0 + l31) * E_ + hd * 64;
#pragma unroll
    for (int dt = 0; dt < 2; ++dt)
#pragma unroll
        for (int c = 0; c < 4; ++c) {
            float4 r;
            r.x = o2[dt][c * 4 + 0] * inv;
            r.y = o2[dt][c * 4 + 1] * inv;
            r.z = o2[dt][c * 4 + 2] * inv;
            r.w = o2[dt][c * 4 + 3] * inv;
            *(float4*)(ob + dt * 32 + c * 8 + l5 * 4) = r;
        }
}

// ---------------------------------------------------------------------------
extern "C" void kernel_launch(void* const* d_in, const int* in_sizes, int n_in,
                              void* d_out, int out_size, void* d_ws, size_t ws_size,
                              hipStream_t stream)
{
    const float* x  = (const float*)d_in[0];
    const float* Wq = (const float*)d_in[1];
    const float* bq = (const float*)d_in[2];
    const float* Wk = (const float*)d_in[3];
    const float* bk = (const float*)d_in[4];
    const float* Wv = (const float*)d_in[5];
    const float* bv = (const float*)d_in[6];

    char* ws = (char*)d_ws;
    unsigned short* wt   = (unsigned short*)ws;                       // 393216 B
    float*          bias = (float*)(ws + 393216);                     // 12288 B
    unsigned short* Qg   = (unsigned short*)(ws + 405504);            // 16 MiB
    unsigned short* Kg   = (unsigned short*)(ws + 405504 + 16777216);
    unsigned short* Vtg  = (unsigned short*)(ws + 405504 + 2 * 16777216);
    float* outp = (float*)d_out;

    hipLaunchKernelGGL(prep_kernel, dim3(192),  dim3(256), 0, stream,
                       Wq, bq, Wk, bk, Wv, bv, wt, bias);
    hipLaunchKernelGGL(proj_kernel, dim3(2048), dim3(256), 0, stream,
                       x, wt, bias, Qg, Kg, Vtg);
    hipLaunchKernelGGL(attn_kernel, dim3(1024), dim3(256), 0, stream,
                       Qg, Kg, Vtg, outp);
}

// Round 8
// 207.594 us; speedup vs baseline: 1.0423x; 1.0423x over previous
//
#include <hip/hip_runtime.h>

#define B_ 4
#define S_ 2048
#define E_ 1024
#define H_ 16
#define D_ 64
#define BH_ (B_*H_)
#define SD_ (S_*D_)

// log2(e)/8 : folds both 1/sqrt(D) and the exp->exp2 conversion into Q
#define QSCALE 0.18033688011112042f

typedef __attribute__((ext_vector_type(4))) float f32x4;
typedef __attribute__((ext_vector_type(16))) float f32x16;
typedef __attribute__((ext_vector_type(8))) short bf16x8;
typedef __attribute__((ext_vector_type(2))) unsigned int uint2v;

#define MFMA(a,b,c)   __builtin_amdgcn_mfma_f32_16x16x32_bf16((a),(b),(c),0,0,0)
#define MFMA32(a,b,c) __builtin_amdgcn_mfma_f32_32x32x16_bf16((a),(b),(c),0,0,0)

__device__ __forceinline__ unsigned short f2bf(float f) {
    unsigned int u = __float_as_uint(f);
    unsigned int r = (u + 0x7fffu + ((u >> 16) & 1u)) >> 16;   // RNE
    return (unsigned short)r;
}
__device__ __forceinline__ unsigned int cvtpk(float a, float b) {
    unsigned int r;
    asm("v_cvt_pk_bf16_f32 %0, %1, %2" : "=v"(r) : "v"(a), "v"(b));
    return r;
}
__device__ __forceinline__ float exp2fast(float x) {
    float r;
    asm("v_exp_f32 %0, %1" : "=v"(r) : "v"(x));
    return r;
}
__device__ __forceinline__ float max3f(float a, float b, float c) {
    float r;
    asm("v_max3_f32 %0, %1, %2, %3" : "=v"(r) : "v"(a), "v"(b), "v"(c));
    return r;
}
__device__ __forceinline__ void gload16(const void* g, void* l) {
    __builtin_amdgcn_global_load_lds(
        (const __attribute__((address_space(1))) unsigned int*)g,
        (__attribute__((address_space(3))) unsigned int*)l, 16, 0, 0);
}

// ---------------------------------------------------------------------------
// prep: W[h][d][e] fp32 -> Wt[mat][h][e][d] bf16 (Q pre-scaled), bias fp32
// ---------------------------------------------------------------------------
__global__ __launch_bounds__(256) void prep_kernel(
    const float* __restrict__ Wq, const float* __restrict__ bq,
    const float* __restrict__ Wk, const float* __restrict__ bk,
    const float* __restrict__ Wv, const float* __restrict__ bv,
    unsigned short* __restrict__ wt, float* __restrict__ bias)
{
    const int blk = blockIdx.x;            // 192 = 3 mats * 16 heads * 4 dchunks
    const int mat = blk >> 6, rest = blk & 63;
    const int h = rest >> 2, dc = rest & 3;
    const float* W    = (mat == 0) ? Wq : (mat == 1) ? Wk : Wv;
    const float* bsrc = (mat == 0) ? bq : (mat == 1) ? bk : bv;
    const float scale = (mat == 0) ? QSCALE : 1.0f;
    const int tid = threadIdx.x;
#pragma unroll
    for (int i = 0; i < 4; ++i) {
        int idx = tid + i * 256;           // 0..1023
        int d = dc * 16 + (idx >> 6), e = idx & 63;
        wt[((mat * H_ + h) << 12) + e * 64 + d] = f2bf(W[h * 4096 + d * 64 + e] * scale);
    }
    if (dc == 0 && tid < 64) bias[(mat * H_ + h) * 64 + tid] = bsrc[h * 64 + tid] * scale;
}

// ---------------------------------------------------------------------------
// proj (LDS-free, zero barriers): all frags from global; Q, K, V stored as
// TILED CONTIGUOUS images [bh][t][8 dslots][64 rows][8 elems] bf16:
//   Q/K: row = s-in-tile, dslot = d-16B-chunk;  V: row = d, dslot = s-chunk.
// This is exactly the linear LDS image attn's global_load_lds expects, and
// every image read in attn is a contiguous 512B half-wave load.
// ---------------------------------------------------------------------------
__global__ __launch_bounds__(256) void proj_kernel(
    const float* __restrict__ x,
    const unsigned short* __restrict__ wt,
    const float* __restrict__ bias,
    unsigned short* __restrict__ Qg,
    unsigned short* __restrict__ Kg,
    unsigned short* __restrict__ Vtg)
{
    const int blk = blockIdx.x;                    // 2048
    const int bh  = blk >> 5;
    const int t_  = blk & 31;                      // s-tile index
    const int s0  = t_ << 6;
    const int batch = bh >> 4, h = bh & 15;
    const int tid = threadIdx.x, lane = tid & 63, w = tid >> 6;
    const int lo = lane & 15, hi = lane >> 4;

    // X fragments direct from global fp32 (B-frag for Q/K, A-frag for V):
    // lane holds X[s = w*16+lo][d = hi*8..+8] and [32+hi*8..+8]
    const float* xr = x + (size_t)(batch * S_ + s0 + w * 16 + lo) * E_ + h * 64;
    float4 xa = *(const float4*)(xr + hi * 8);
    float4 xb = *(const float4*)(xr + hi * 8 + 4);
    float4 xc = *(const float4*)(xr + 32 + hi * 8);
    float4 xd = *(const float4*)(xr + 32 + hi * 8 + 4);
    union BF { bf16x8 v; unsigned int u[4]; };
    BF xf0, xf1;
    xf0.u[0] = cvtpk(xa.x, xa.y); xf0.u[1] = cvtpk(xa.z, xa.w);
    xf0.u[2] = cvtpk(xb.x, xb.y); xf0.u[3] = cvtpk(xb.z, xb.w);
    xf1.u[0] = cvtpk(xc.x, xc.y); xf1.u[1] = cvtpk(xc.z, xc.w);
    xf1.u[2] = cvtpk(xd.x, xd.y); xf1.u[3] = cvtpk(xd.z, xd.w);

    const size_t ibase = (size_t)bh * SD_ + t_ * 4096;   // image tile base (elems)

    // Q, K: C[e][s] = Wt . X^T -> thread holds e = et*16+hi*4+(0..3), s = w*16+lo
#pragma unroll
    for (int mat = 0; mat < 2; ++mat) {
        const unsigned short* wm = wt + ((mat * H_ + h) << 12);
        unsigned short* Og = mat ? Kg : Qg;
#pragma unroll
        for (int et = 0; et < 4; ++et) {
            const unsigned short* wr = wm + (et * 16 + lo) * 64;
            bf16x8 wa0 = *(const bf16x8*)(wr + hi * 8);
            bf16x8 wa1 = *(const bf16x8*)(wr + 32 + hi * 8);
            f32x4 acc = {0.f, 0.f, 0.f, 0.f};
            acc = MFMA(wa0, xf0.v, acc);
            acc = MFMA(wa1, xf1.v, acc);
            f32x4 bv = *(const f32x4*)(bias + (mat * H_ + h) * 64 + et * 16 + hi * 4);
            acc += bv;
            uint2 pk;
            pk.x = cvtpk(acc[0], acc[1]);
            pk.y = cvtpk(acc[2], acc[3]);
            // image store: dslot = et*2+(hi>>1), row = w*16+lo, sub = (hi&1)*4
            int off = ((et * 2 + (hi >> 1)) * 64 + w * 16 + lo) * 8 + (hi & 1) * 4;
            *(uint2*)(Og + ibase + off) = pk;
        }
    }
    // V: C[s][e] = X . Wv -> thread holds s = w*16+hi*4+(0..3), e = nt*16+lo
#pragma unroll
    for (int nt = 0; nt < 4; ++nt) {
        const unsigned short* wr = wt + ((2 * H_ + h) << 12) + (nt * 16 + lo) * 64;
        bf16x8 wb0 = *(const bf16x8*)(wr + hi * 8);
        bf16x8 wb1 = *(const bf16x8*)(wr + 32 + hi * 8);
        f32x4 acc = {0.f, 0.f, 0.f, 0.f};
        acc = MFMA(xf0.v, wb0, acc);
        acc = MFMA(xf1.v, wb1, acc);
        float bvv = bias[(2 * H_ + h) * 64 + nt * 16 + lo];
        acc += bvv;
        uint2 pk;
        pk.x = cvtpk(acc[0], acc[1]);
        pk.y = cvtpk(acc[2], acc[3]);
        // V image: row = d = nt*16+lo, dslot = s-chunk = w*2+(hi>>1)
        int off = ((w * 2 + (hi >> 1)) * 64 + nt * 16 + lo) * 8 + (hi & 1) * 4;
        *(uint2*)(Vtg + ibase + off) = pk;
    }
}

// ---------------------------------------------------------------------------
// attn: flash attention, swapped QK^T with 32x32x16 MFMA, KVBLK=64,
// 4 waves x 32 q (QBLK=128); global_load_lds double-buffer of contiguous
// images; m folded into MFMA C-init; l via ones-MFMA accumulated across
// tiles; LDS-transpose epilogue (XOR-swizzled) for full-line fp32 stores.
// ---------------------------------------------------------------------------
__global__ __launch_bounds__(256, 4) void attn_kernel(
    const unsigned short* __restrict__ Qg,
    const unsigned short* __restrict__ Kg,
    const unsigned short* __restrict__ Vtg,
    float* __restrict__ outp)
{
    __shared__ char smem[32768];   // [0,16K): K dbuf, [16K,32K): V dbuf; epilogue reuse

    const int blk = blockIdx.x;                 // 1024, XCD-bijective swizzle
    const int bh  = (blk & 7) + ((blk >> 7) << 3);
    const int qt  = (blk >> 3) & 15;
    const int batch = bh >> 4, hd = bh & 15;
    const int tid = threadIdx.x, lane = tid & 63, w = tid >> 6;  // w = 0..3
    const int l31 = lane & 31, l5 = lane >> 5;

    const unsigned short* Qb = Qg + (size_t)bh * SD_;
    const char* Kt = (const char*)(Kg  + (size_t)bh * SD_);   // +t*8192 bytes
    const char* Vt = (const char*)(Vtg + (size_t)bh * SD_);

    // Q B-frags from Q image: lane holds Q[q][d = ds*16 + l5*8 .. +8]
    // q = qt*128 + w*32 + l31 -> image tile tq = qt*2+(w>>1), row (w&1)*32+l31
    const unsigned short* Qtile = Qb + (qt * 2 + (w >> 1)) * 4096;
    const int qrow = (w & 1) * 32 + l31;
    bf16x8 qf[4];
#pragma unroll
    for (int ds = 0; ds < 4; ++ds)
        qf[ds] = *(const bf16x8*)(Qtile + ((ds * 2 + l5) * 64 + qrow) * 8);

    bf16x8 ones8;
#pragma unroll
    for (int j = 0; j < 8; ++j) ones8[j] = (short)0x3F80;

    const int goff = w * 2048 + lane * 16;   // this lane's byte chunk in tile

    f32x16 o2[2], lzacc, mi;
#pragma unroll
    for (int i = 0; i < 16; ++i) {
        o2[0][i] = 0.f; o2[1][i] = 0.f; lzacc[i] = 0.f; mi[i] = 0.f;
    }
    float m_run = 0.0f;

    // prologue: stage tile 0 into buf0 (2KB per wave per buffer, 2 instr each)
    gload16(Kt + goff,        smem + w * 2048);
    gload16(Kt + goff + 1024, smem + w * 2048 + 1024);
    gload16(Vt + goff,        smem + 16384 + w * 2048);
    gload16(Vt + goff + 1024, smem + 16384 + w * 2048 + 1024);
    __syncthreads();

#pragma unroll 1
    for (int t = 0; t < 32; ++t) {
        const unsigned short* kl = (const unsigned short*)(smem + (t & 1) * 8192);
        const unsigned short* vl = (const unsigned short*)(smem + 16384 + (t & 1) * 8192);
        if (t + 1 < 32) {
            char* kd = smem + ((t + 1) & 1) * 8192 + w * 2048;
            char* vd = smem + 16384 + ((t + 1) & 1) * 8192 + w * 2048;
            const int tb = (t + 1) * 8192;
            gload16(Kt + tb + goff,        kd);
            gload16(Kt + tb + goff + 1024, kd + 1024);
            gload16(Vt + tb + goff,        vd);
            gload16(Vt + tb + goff + 1024, vd + 1024);
        }

        // S^T[k][q] - m = K . Q^T + mi   (2 k-subtiles of 32)
        // K image read: dslot = 2ds+l5 -> contiguous 512B per half-wave
        f32x16 st0 = mi, st1 = mi;
        __builtin_amdgcn_s_setprio(1);
#pragma unroll
        for (int ds = 0; ds < 4; ++ds) {
            bf16x8 ka0 = *(const bf16x8*)(kl + (2 * ds + l5) * 512 + l31 * 8);
            bf16x8 ka1 = *(const bf16x8*)(kl + (2 * ds + l5) * 512 + 256 + l31 * 8);
            st0 = MFMA32(ka0, qf[ds], st0);
            st1 = MFMA32(ka1, qf[ds], st1);
        }
        __builtin_amdgcn_s_setprio(0);

        // row max of 32 shifted scores (max3 tree) + cross-half reduce
        float c0 = max3f(st0[0], st0[1], st0[2]);
        float c1 = max3f(st0[3], st0[4], st0[5]);
        float c2 = max3f(st0[6], st0[7], st0[8]);
        float c3 = max3f(st0[9], st0[10], st0[11]);
        float c4 = max3f(st0[12], st0[13], st0[14]);
        float c5 = max3f(st0[15], st1[0], st1[1]);
        float c6 = max3f(st1[2], st1[3], st1[4]);
        float c7 = max3f(st1[5], st1[6], st1[7]);
        float c8 = max3f(st1[8], st1[9], st1[10]);
        float c9 = max3f(st1[11], st1[12], st1[13]);
        float ca = fmaxf(st1[14], st1[15]);
        float d0 = max3f(c0, c1, c2);
        float d1 = max3f(c3, c4, c5);
        float d2 = max3f(c6, c7, c8);
        float d3 = max3f(c9, ca, d0);
        float mx = max3f(d1, d2, d3);
        mx = fmaxf(mx, __shfl_xor(mx, 32));

        // defer-max (T13): rescale only when max grew by > 8 over m_run
        if (!__all(mx <= 8.0f)) {
            float delta = fmaxf(mx, 0.0f);
            float alpha = exp2fast(-delta);
#pragma unroll
            for (int i = 0; i < 16; ++i) {
                o2[0][i] *= alpha; o2[1][i] *= alpha; lzacc[i] *= alpha;
                st0[i] -= delta;   st1[i] -= delta;   mi[i]   -= delta;
            }
            m_run += delta;
        }

        // P = exp2(st) -> bf16 pairs -> B-frags via permlane32_swap
        union F { bf16x8 v; unsigned int u[4]; };
        F pb[2][2];
#pragma unroll
        for (int kt = 0; kt < 2; ++kt) {
            const f32x16& s = kt ? st1 : st0;
            unsigned int u0 = cvtpk(exp2fast(s[0]),  exp2fast(s[1]));
            unsigned int u1 = cvtpk(exp2fast(s[2]),  exp2fast(s[3]));
            unsigned int u2 = cvtpk(exp2fast(s[4]),  exp2fast(s[5]));
            unsigned int u3 = cvtpk(exp2fast(s[6]),  exp2fast(s[7]));
            unsigned int u4 = cvtpk(exp2fast(s[8]),  exp2fast(s[9]));
            unsigned int u5 = cvtpk(exp2fast(s[10]), exp2fast(s[11]));
            unsigned int u6 = cvtpk(exp2fast(s[12]), exp2fast(s[13]));
            unsigned int u7 = cvtpk(exp2fast(s[14]), exp2fast(s[15]));
            uint2v sA = __builtin_amdgcn_permlane32_swap(u0, u2, false, false);
            uint2v sB = __builtin_amdgcn_permlane32_swap(u1, u3, false, false);
            pb[kt][0].u[0] = sA.x; pb[kt][0].u[1] = sB.x;
            pb[kt][0].u[2] = sA.y; pb[kt][0].u[3] = sB.y;
            uint2v sC = __builtin_amdgcn_permlane32_swap(u4, u6, false, false);
            uint2v sD = __builtin_amdgcn_permlane32_swap(u5, u7, false, false);
            pb[kt][1].u[0] = sC.x; pb[kt][1].u[1] = sD.x;
            pb[kt][1].u[2] = sC.y; pb[kt][1].u[3] = sD.y;
        }

        // l row-sum via ones-MFMA (accumulated across tiles) + O += V^T . P^T
        __builtin_amdgcn_s_setprio(1);
        lzacc = MFMA32(ones8, pb[0][0].v, lzacc);
        lzacc = MFMA32(ones8, pb[0][1].v, lzacc);
        lzacc = MFMA32(ones8, pb[1][0].v, lzacc);
        lzacc = MFMA32(ones8, pb[1][1].v, lzacc);
#pragma unroll
        for (int dt = 0; dt < 2; ++dt) {
#pragma unroll
            for (int ksb = 0; ksb < 4; ++ksb) {
                // V image read: row = dt*32+l31, dslot = ksb*2+l5 (contig 512B)
                bf16x8 va = *(const bf16x8*)(vl + (ksb * 2 + l5) * 512 +
                                             dt * 256 + l31 * 8);
                o2[dt] = MFMA32(va, pb[ksb >> 1][ksb & 1].v, o2[dt]);
            }
        }
        __builtin_amdgcn_s_setprio(0);

        __syncthreads();
    }

    // epilogue: normalize, transpose via LDS (staging bufs dead; XOR-swizzled
    // chunk index on both sides to stay at the bank floor), full-line stores
    const float inv = 1.0f / lzacc[0];
    char* sm = smem + w * 8192;              // 8KB per wave: 32 q-rows x 256B
#pragma unroll
    for (int dt = 0; dt < 2; ++dt)
#pragma unroll
        for (int g = 0; g < 4; ++g) {
            f32x4 r;
            r[0] = o2[dt][g * 4 + 0] * inv;
            r[1] = o2[dt][g * 4 + 1] * inv;
            r[2] = o2[dt][g * 4 + 2] * inv;
            r[3] = o2[dt][g * 4 + 3] * inv;
            int idx = dt * 8 + g * 2 + l5;               // logical 16B chunk (d)
            *(f32x4*)(sm + l31 * 256 + (idx ^ (l31 & 7)) * 16) = r;
        }
    __syncthreads();
    float* ob0 = outp + (size_t)(batch * S_ + qt * 128 + w * 32) * E_ + hd * 64;
#pragma unroll
    for (int r8 = 0; r8 < 8; ++r8) {
        int row = (r8 & 1) * 16 + (lane >> 2);           // local q row 0..31
        int ch  = (r8 >> 1) * 4 + (lane & 3);            // logical d-chunk 0..15
        f32x4 v = *(const f32x4*)(smem + w * 8192 + row * 256 + (ch ^ (row & 7)) * 16);
        *(f32x4*)(ob0 + row * E_ + ch * 4) = v;
    }
}

// ---------------------------------------------------------------------------
extern "C" void kernel_launch(void* const* d_in, const int* in_sizes, int n_in,
                              void* d_out, int out_size, void* d_ws, size_t ws_size,
                              hipStream_t stream)
{
    const float* x  = (const float*)d_in[0];
    const float* Wq = (const float*)d_in[1];
    const float* bq = (const float*)d_in[2];
    const float* Wk = (const float*)d_in[3];
    const float* bk = (const float*)d_in[4];
    const float* Wv = (const float*)d_in[5];
    const float* bv = (const float*)d_in[6];

    char* ws = (char*)d_ws;
    unsigned short* wt   = (unsigned short*)ws;                       // 393216 B
    float*          bias = (float*)(ws + 393216);                     // 12288 B
    unsigned short* Qg   = (unsigned short*)(ws + 405504);            // 16 MiB
    unsigned short* Kg   = (unsigned short*)(ws + 405504 + 16777216);
    unsigned short* Vtg  = (unsigned short*)(ws + 405504 + 2 * 16777216);
    float* outp = (float*)d_out;

    hipLaunchKernelGGL(prep_kernel, dim3(192),  dim3(256), 0, stream,
                       Wq, bq, Wk, bk, Wv, bv, wt, bias);
    hipLaunchKernelGGL(proj_kernel, dim3(2048), dim3(256), 0, stream,
                       x, wt, bias, Qg, Kg, Vtg);
    hipLaunchKernelGGL(attn_kernel, dim3(1024), dim3(256), 0, stream,
                       Qg, Kg, Vtg, outp);
}